// Round 8
// baseline (533.795 us; speedup 1.0000x reference)
//
#include <hip/hip_runtime.h>
#include <math.h>

#define B_    32
#define HH    56
#define WW_   56
#define C_    192
#define WS_   7
#define SHIFT_ 3
#define HEADS_ 6
#define DH    32
#define N_    49
#define NWIN  2048
#define ROWS  100352
#define HID_  768
#define QKVN  576

typedef __bf16 bfr;
typedef __bf16 bf8 __attribute__((ext_vector_type(8)));
typedef __bf16 bf4 __attribute__((ext_vector_type(4)));
typedef float  f32x4 __attribute__((ext_vector_type(4)));

#define MFMA16(a,b,c) __builtin_amdgcn_mfma_f32_16x16x32_bf16(a,b,c,0,0,0)

// ---- ws layout (bf16 elements) ----
#define OQW   0         // qkvwT [576][192]
#define OPW   110592    // projwT[192][192]
#define OW1   147456    // w1T   [768][192]
#define OW2   294912    // w2T   [192][768]
#define OBM   442368    // bmask [6][4cls][64 q][64 k]  ROW-major q,k (pads=-1e30)
#define WTOT  442368
#define BMTOT 98304     // 6*4*64*64  (4 window classes: (wh==7)x(ww==7))

// ================= k_prep: transpose + fp32->bf16 all weights =================
__global__ __launch_bounds__(256) void k_prep(
    const float* __restrict__ qkvw, const float* __restrict__ projw,
    const float* __restrict__ w1,   const float* __restrict__ w2,
    bfr* __restrict__ wsp)
{
  int idx = blockIdx.x*256 + threadIdx.x;
  if (idx >= WTOT) return;
  if (idx < OPW)      { int i=idx;      int n=i/192, k=i%192; wsp[idx] = (bfr)qkvw[k*QKVN + n]; }
  else if (idx < OW1) { int i=idx-OPW;  int n=i/192, k=i%192; wsp[idx] = (bfr)projw[k*C_ + n]; }
  else if (idx < OW2) { int i=idx-OW1;  int n=i/192, k=i%192; wsp[idx] = (bfr)w1[k*HID_ + n]; }
  else                { int i=idx-OW2;  int n=i/768, k=i%768; wsp[idx] = (bfr)w2[k*C_ + n]; }
}

// ====== k_prep2: bmask[head][cls][q64][k64] = bias + mask (pads -1e30), k fastest ======
// Mask depends on (wh,ww) only through (wh==7, ww==7): 4 classes.
__global__ __launch_bounds__(256) void k_prep2(
    const float* __restrict__ btab, const int* __restrict__ rel,
    const float* __restrict__ mask, bfr* __restrict__ bm)
{
  int idx = blockIdx.x*256 + threadIdx.x;   // [head][cls][q][k] -- k fastest
  if (idx >= BMTOT) return;
  int k = idx & 63, q = (idx>>6) & 63, cls = (idx>>12) & 3, head = idx>>14;
  int wh = (cls & 2) ? 7 : 0, ww = (cls & 1) ? 7 : 0;
  int wi = wh*8 + ww;
  float v = -1e30f;
  if (q < N_ && k < N_) {
    int e = q*N_ + k;
    v = btab[rel[e]*HEADS_ + head] + mask[(size_t)wi*N_*N_ + e];
  }
  bm[idx] = (bfr)v;
}

// ================= Kernel 1: LN1+shift+QKV+attn+proj+residual, head-pair fused ============
// All LDS-bound MFMA outputs use SWAPPED operands (mfma(B,A,C) = D^T): lane then holds
// 4 consecutive COLUMNS (quad*4+r) of one token row (ln15) -> packed b64/b128 stores.
// LDS (bytes):
#define SM_HS 0        // bfr hs[64][200]          25600  (LN'd input, persists)
#define SM_QS 25600    // bfr qs[2][64][36]         9216
#define SM_KS 34816    // bfr ks[2][64][36]         9216
#define SM_VT 44032    // bfr vT[2][32][72]         9216
#define SM_P  53248    // bfr P[64][72]             9216  (wave-row-local scratch)
#define SM_OV 62464    // bfr ov2[64][72]           9216  (both heads: [row][hl*36+d])
#define SM_SR 71680    // int srows[64]              256
#define SM1_TOT 71936
#define HSP 200

__global__ __launch_bounds__(256, 2) void k_attn(
    const float* __restrict__ x,
    const float* __restrict__ n1w, const float* __restrict__ n1b,
    const bfr*   __restrict__ wsp,
    const float* __restrict__ qkvb,
    const float* __restrict__ projb,
    float* __restrict__ out)
{
  __shared__ char smem[SM1_TOT];
  bfr*   hs    = (bfr*)(smem + SM_HS);
  bfr*   qs    = (bfr*)(smem + SM_QS);
  bfr*   ks    = (bfr*)(smem + SM_KS);
  bfr*   vT    = (bfr*)(smem + SM_VT);
  bfr*   P     = (bfr*)(smem + SM_P);
  bfr*   ov2   = (bfr*)(smem + SM_OV);
  int*   srows = (int*)(smem + SM_SR);
  float* pj    = (float*)smem;   // overlay [64][196] fp32 = 50176 B over hs/qs/ks/vT

  const f32x4 ZERO4 = {0.f, 0.f, 0.f, 0.f};

  int win  = blockIdx.x;
  int tid  = threadIdx.x;
  int lane = tid & 63, wave = tid >> 6;
  int ln15 = lane & 15, quad = lane >> 4;
  int wi   = win & 63;
  int cls  = (((wi>>3)==7) ? 2 : 0) + (((wi&7)==7) ? 1 : 0);

  // ---- srows + zero hs pad rows (49..63 only) ----
  if (tid < N_) {
    int bb = win >> 6;
    int wh = wi >> 3, ww = wi & 7;
    int th = tid / WS_, tw = tid % WS_;
    int sh = wh*WS_ + th + SHIFT_; if (sh >= HH) sh -= HH;
    int sw = ww*WS_ + tw + SHIFT_; if (sw >= WW_) sw -= WW_;
    srows[tid] = bb*HH*WW_ + sh*WW_ + sw;
  }
  {
    int* hz = (int*)(hs + 49*HSP);
    for (int i = tid; i < 15*HSP/2; i += 256) hz[i] = 0;
  }
  __syncthreads();
  // ---- LN1 -> hs ----
  for (int r = wave; r < N_; r += 4) {
    const float* xr = x + (size_t)srows[r]*C_;
    float v0 = xr[lane], v1 = xr[lane+64], v2 = xr[lane+128];
    float s = v0+v1+v2, q = v0*v0+v1*v1+v2*v2;
    #pragma unroll
    for (int m = 32; m; m >>= 1) { s += __shfl_xor(s, m); q += __shfl_xor(q, m); }
    float mu = s*(1.f/C_), var = q*(1.f/C_) - mu*mu;
    float rs = rsqrtf(var + 1e-5f);
    hs[r*HSP + lane]     = (bfr)((v0-mu)*rs*n1w[lane]     + n1b[lane]);
    hs[r*HSP + lane+64]  = (bfr)((v1-mu)*rs*n1w[lane+64]  + n1b[lane+64]);
    hs[r*HSP + lane+128] = (bfr)((v2-mu)*rs*n1w[lane+128] + n1b[lane+128]);
  }
  __syncthreads();

  const bfr* qkvwT  = wsp + OQW;
  const bfr* projwT = wsp + OPW;
  const bfr* bmask  = wsp + OBM;

  f32x4 accp[3][4];   // proj accumulators (swapped layout: [outcol4][token]), persist
  #pragma unroll
  for (int j=0;j<3;j++)
    #pragma unroll
    for (int mt=0;mt<4;mt++) accp[j][mt] = ZERO4;

  for (int pair = 0; pair < 3; pair++) {
    // ---- QKV: q,k SWAPPED (packed col-stores); v normal (packed row-stores) ----
    {
      f32x4 qb0 = *(const f32x4*)&qkvb[       pair*64 + wave*16 + quad*4];
      f32x4 qb1 = *(const f32x4*)&qkvb[192  + pair*64 + wave*16 + quad*4];
      float qb2 =                 qkvb[384  + pair*64 + wave*16 + ln15];
      f32x4 acc[3][4];
      #pragma unroll
      for (int j=0;j<3;j++)
        #pragma unroll
        for (int mt=0;mt<4;mt++) acc[j][mt] = ZERO4;
      #pragma unroll
      for (int kk = 0; kk < 6; kk++) {
        bf8 afr[4];
        #pragma unroll
        for (int mt=0;mt<4;mt++)
          afr[mt] = *(const bf8*)&hs[(mt*16+ln15)*HSP + kk*32 + quad*8];
        bf8 bw0 = *(const bf8*)&qkvwT[(size_t)(      pair*64 + wave*16 + ln15)*192 + kk*32 + quad*8];
        bf8 bw1 = *(const bf8*)&qkvwT[(size_t)(192 + pair*64 + wave*16 + ln15)*192 + kk*32 + quad*8];
        bf8 bw2 = *(const bf8*)&qkvwT[(size_t)(384 + pair*64 + wave*16 + ln15)*192 + kk*32 + quad*8];
        #pragma unroll
        for (int mt=0;mt<4;mt++) {
          acc[0][mt] = MFMA16(bw0, afr[mt], acc[0][mt]);   // swapped -> D[qcol][token]
          acc[1][mt] = MFMA16(bw1, afr[mt], acc[1][mt]);   // swapped
          acc[2][mt] = MFMA16(afr[mt], bw2, acc[2][mt]);   // normal  -> D[token][vcol]
        }
      }
      int hlw = wave >> 1;
      int d0  = (wave & 1)*16 + quad*4;       // q/k col base (4 consecutive)
      int dv  = (wave & 1)*16 + ln15;         // v col (fixed per lane)
      #pragma unroll
      for (int mt=0;mt<4;mt++) {
        int token = mt*16 + ln15;
        bf4 pk;
        #pragma unroll
        for (int r=0;r<4;r++) pk[r] = (bfr)((acc[0][mt][r] + qb0[r])*0.17677669529663689f);
        *(bf4*)&qs[(hlw*64+token)*36 + d0] = pk;
        #pragma unroll
        for (int r=0;r<4;r++) pk[r] = (bfr)(acc[1][mt][r] + qb1[r]);
        *(bf4*)&ks[(hlw*64+token)*36 + d0] = pk;
        #pragma unroll
        for (int r=0;r<4;r++) pk[r] = (bfr)(acc[2][mt][r] + qb2);   // 4 consecutive tokens
        *(bf4*)&vT[(hlw*32+dv)*72 + mt*16 + quad*4] = pk;
      }
    }
    __syncthreads();

    // ---- bmask burst [q][k]: lane q=wave*16+ln15, 4 consecutive k ----
    bf4 bm4[2][4];
    #pragma unroll
    for (int hl = 0; hl < 2; hl++) {
      const bfr* bmh = bmask + (((size_t)(pair*2+hl)*4 + cls) << 12);
      #pragma unroll
      for (int nt = 0; nt < 4; nt++)
        bm4[hl][nt] = *(const bf4*)&bmh[(wave*16+ln15)*64 + nt*16 + quad*4];
    }

    // ---- QK^T SWAPPED: D[k][q]; lane holds 16 k-values for q=wave*16+ln15 ----
    float val[2][4][4];   // [hl][nt][r], k = nt*16+quad*4+r
    #pragma unroll
    for (int hl = 0; hl < 2; hl++) {
      bf8 aq = *(const bf8*)&qs[(hl*64 + wave*16 + ln15)*36 + quad*8];
      #pragma unroll
      for (int nt = 0; nt < 4; nt++) {
        f32x4 c;
        c[0] = (float)bm4[hl][nt][0]; c[1] = (float)bm4[hl][nt][1];
        c[2] = (float)bm4[hl][nt][2]; c[3] = (float)bm4[hl][nt][3];
        bf8 bk = *(const bf8*)&ks[(hl*64 + nt*16 + ln15)*36 + quad*8];
        c = MFMA16(bk, aq, c);                       // swapped
        #pragma unroll
        for (int r=0;r<4;r++) val[hl][nt][r] = c[r];
      }
    }

    // ---- proj-weight prefetch (6x 16B): latency hides under softmax ----
    bf8 pw[2][3];
    #pragma unroll
    for (int hl = 0; hl < 2; hl++)
      #pragma unroll
      for (int j = 0; j < 3; j++)
        pw[hl][j] = *(const bf8*)&projwT[(size_t)((wave*3+j)*16 + ln15)*192
                                         + (pair*2+hl)*32 + quad*8];

    // ---- per head: softmax (15 VALU + 2 shfl per reduce) + packed P + PV -> ov2 ----
    #pragma unroll
    for (int hl = 0; hl < 2; hl++) {
      float mx = val[hl][0][0];
      #pragma unroll
      for (int nt=0;nt<4;nt++)
        #pragma unroll
        for (int r=0;r<4;r++) mx = fmaxf(mx, val[hl][nt][r]);
      mx = fmaxf(mx, __shfl_xor(mx, 16));
      mx = fmaxf(mx, __shfl_xor(mx, 32));
      float sum = 0.f;
      #pragma unroll
      for (int nt=0;nt<4;nt++)
        #pragma unroll
        for (int r=0;r<4;r++) { val[hl][nt][r] = __expf(val[hl][nt][r] - mx); sum += val[hl][nt][r]; }
      sum += __shfl_xor(sum, 16);
      sum += __shfl_xor(sum, 32);
      float rsum = 1.f / sum;
      #pragma unroll
      for (int nt=0;nt<4;nt++) {
        bf4 pk;
        #pragma unroll
        for (int r=0;r<4;r++) pk[r] = (bfr)(val[hl][nt][r]*rsum);
        *(bf4*)&P[(wave*16+ln15)*72 + nt*16 + quad*4] = pk;     // own q-row, packed
      }
      // PV SWAPPED: D[d][q]; wave reads ONLY its own P rows -> no barrier
      bf8 ap0 = *(const bf8*)&P[(wave*16+ln15)*72 + quad*8];
      bf8 ap1 = *(const bf8*)&P[(wave*16+ln15)*72 + 32 + quad*8];
      #pragma unroll
      for (int nt = 0; nt < 2; nt++) {
        bf8 bv0 = *(const bf8*)&vT[(hl*32 + nt*16 + ln15)*72 + quad*8];
        bf8 bv1 = *(const bf8*)&vT[(hl*32 + nt*16 + ln15)*72 + 32 + quad*8];
        f32x4 c = MFMA16(bv0, ap0, ZERO4);
        c = MFMA16(bv1, ap1, c);
        bf4 pk;
        #pragma unroll
        for (int r=0;r<4;r++) pk[r] = (bfr)c[r];
        *(bf4*)&ov2[(wave*16+ln15)*72 + hl*36 + nt*16 + quad*4] = pk;
      }
    }
    __syncthreads();

    // ---- proj K-step SWAPPED (K=64: both heads), weights already in regs ----
    #pragma unroll
    for (int hl = 0; hl < 2; hl++) {
      bf8 afr[4];
      #pragma unroll
      for (int mt=0;mt<4;mt++)
        afr[mt] = *(const bf8*)&ov2[(mt*16+ln15)*72 + hl*36 + quad*8];
      #pragma unroll
      for (int j=0;j<3;j++)
        #pragma unroll
        for (int mt=0;mt<4;mt++) accp[j][mt] = MFMA16(pw[hl][j], afr[mt], accp[j][mt]);
    }
    // no barrier: next pair's QKV writes qs/ks/vT; all reads of them finished pre-ov2-barrier
  }

  // ---- epilogue: bias -> pj overlay (b128 packed) -> coalesced residual+scatter ----
  // (No barrier needed before pj writes: after the final ov2-barrier nobody reads hs..vT.)
  #pragma unroll
  for (int j=0;j<3;j++) {
    int col0 = (wave*3+j)*16 + quad*4;
    f32x4 pb = *(const f32x4*)&projb[col0];
    #pragma unroll
    for (int mt=0;mt<4;mt++) {
      f32x4 w;
      #pragma unroll
      for (int r=0;r<4;r++) w[r] = accp[j][mt][r] + pb[r];
      *(f32x4*)&pj[(mt*16+ln15)*196 + col0] = w;
    }
  }
  __syncthreads();
  for (int idx = tid; idx < N_*C_; idx += 256) {
    int n = idx / C_, c = idx % C_;
    size_t gr = (size_t)srows[n]*C_ + c;
    out[gr] = x[gr] + pj[n*196 + c];
  }
}

// ================= Kernel 2: LN2 + fc1 + GELU + fc2 + residual, 64 rows/block ================
// fc1/fc2 SWAPPED -> packed b64 hidc stores and b128 st stores.
// LDS: ts[64][200] (25600) + hidc[64][200] (25600) = 51200 B -> 3 blocks/CU.
#define SM2_TS  0
#define SM2_HID 25600
#define SM2_TOT 51200

__global__ __launch_bounds__(256, 2) void k_mlp(
    float* __restrict__ y,
    const float* __restrict__ n2w, const float* __restrict__ n2b,
    const bfr* __restrict__ wsp,
    const float* __restrict__ b1, const float* __restrict__ b2)
{
  __shared__ char smem[SM2_TOT];
  bfr*   ts   = (bfr*)(smem + SM2_TS);
  bfr*   hidc = (bfr*)(smem + SM2_HID);
  float* st   = (float*)smem;       // overlay after ts/hidc dead

  const f32x4 ZERO4 = {0.f, 0.f, 0.f, 0.f};

  int r0 = blockIdx.x * 64;
  int tid = threadIdx.x;
  int lane = tid & 63, wave = tid >> 6;
  int ln15 = lane & 15, quad = lane >> 4;

  // ---- LN2 ----
  #pragma unroll
  for (int i = 0; i < 16; i++) {
    int r = wave + i*4;
    const float* yr = y + (size_t)(r0 + r)*C_;
    float v0 = yr[lane], v1 = yr[lane+64], v2 = yr[lane+128];
    float s = v0+v1+v2, q = v0*v0+v1*v1+v2*v2;
    #pragma unroll
    for (int m = 32; m; m >>= 1) { s += __shfl_xor(s, m); q += __shfl_xor(q, m); }
    float mu = s*(1.f/C_), var = q*(1.f/C_) - mu*mu;
    float rs = rsqrtf(var + 1e-5f);
    ts[r*HSP + lane]     = (bfr)((v0-mu)*rs*n2w[lane]     + n2b[lane]);
    ts[r*HSP + lane+64]  = (bfr)((v1-mu)*rs*n2w[lane+64]  + n2b[lane+64]);
    ts[r*HSP + lane+128] = (bfr)((v2-mu)*rs*n2w[lane+128] + n2b[lane+128]);
  }
  __syncthreads();

  const bfr* w1T = wsp + OW1;
  const bfr* w2T = wsp + OW2;

  f32x4 accp[3][4];   // fc2 accumulators (swapped layout), persist across chunks
  #pragma unroll
  for (int j=0;j<3;j++)
    #pragma unroll
    for (int mt=0;mt<4;mt++) accp[j][mt] = ZERO4;

  for (int c = 0; c < 4; c++) {
    // ---- fc1 weight burst (18x 16B) + b1 prefetch (f32x4 per j) ----
    bf8 wf1[3][6];
    f32x4 bbv[3];
    #pragma unroll
    for (int j=0;j<3;j++) {
      const bfr* wb = w1T + (size_t)((c*12 + wave*3 + j)*16 + ln15)*192 + quad*8;
      #pragma unroll
      for (int kk=0;kk<6;kk++)
        wf1[j][kk] = *(const bf8*)&wb[kk*32];
      bbv[j] = *(const f32x4*)&b1[c*192 + (wave*3+j)*16 + quad*4];
    }
    // ---- fc1 chunk SWAPPED: D[hidcol][token] ----
    f32x4 acc[3][4];
    #pragma unroll
    for (int j=0;j<3;j++)
      #pragma unroll
      for (int mt=0;mt<4;mt++) acc[j][mt] = ZERO4;
    #pragma unroll
    for (int kk = 0; kk < 6; kk++) {
      bf8 afr[4];
      #pragma unroll
      for (int mt=0;mt<4;mt++)
        afr[mt] = *(const bf8*)&ts[(mt*16+ln15)*HSP + kk*32 + quad*8];
      #pragma unroll
      for (int j=0;j<3;j++)
        #pragma unroll
        for (int mt=0;mt<4;mt++) acc[j][mt] = MFMA16(wf1[j][kk], afr[mt], acc[j][mt]);
    }
    // ---- fc2 weight burst per-j before that j's GELU; packed b64 hidc stores ----
    bf8 wf2[3][6];
    #pragma unroll
    for (int j=0;j<3;j++) {
      const bfr* wb2 = w2T + (size_t)((wave*3+j)*16 + ln15)*768 + c*192 + quad*8;
      #pragma unroll
      for (int kk=0;kk<6;kk++)
        wf2[j][kk] = *(const bf8*)&wb2[kk*32];
      // GELU (tanh-form sigmoid; |err|<3e-4 << bf16 lsb)
      int colc0 = (wave*3 + j)*16 + quad*4;
      #pragma unroll
      for (int mt=0;mt<4;mt++) {
        bf4 pk;
        #pragma unroll
        for (int r=0;r<4;r++) {
          float g = acc[j][mt][r] + bbv[j][r];
          float u = g*(1.5957691216f + 0.0713548170f*g*g);
          pk[r] = (bfr)(g / (1.f + __expf(-u)));
        }
        *(bf4*)&hidc[(mt*16+ln15)*HSP + colc0] = pk;
      }
    }
    __syncthreads();
    // ---- fc2 partial SWAPPED: accp[j][mt] = D[outcol][token] ----
    #pragma unroll
    for (int kk = 0; kk < 6; kk++) {
      bf8 afr[4];
      #pragma unroll
      for (int mt=0;mt<4;mt++)
        afr[mt] = *(const bf8*)&hidc[(mt*16+ln15)*HSP + kk*32 + quad*8];
      #pragma unroll
      for (int j=0;j<3;j++)
        #pragma unroll
        for (int mt=0;mt<4;mt++) accp[j][mt] = MFMA16(wf2[j][kk], afr[mt], accp[j][mt]);
    }
    __syncthreads();   // hidc reads done before next chunk's writes (or st overlay)
  }

  // ---- epilogue: bias -> st overlay (b128 packed) ----
  #pragma unroll
  for (int j=0;j<3;j++) {
    int col0 = (wave*3+j)*16 + quad*4;
    f32x4 bb2 = *(const f32x4*)&b2[col0];
    #pragma unroll
    for (int mt=0;mt<4;mt++) {
      f32x4 w;
      #pragma unroll
      for (int r=0;r<4;r++) w[r] = accp[j][mt][r] + bb2[r];
      *(f32x4*)&st[(mt*16+ln15)*196 + col0] = w;
    }
  }
  __syncthreads();
  // residual, coalesced, in-place
  for (int idx = tid; idx < 64*C_; idx += 256) {
    int r = idx / C_, c = idx % C_;
    size_t gr = (size_t)(r0 + r)*C_ + c;
    y[gr] = y[gr] + st[r*196 + c];
  }
}

extern "C" void kernel_launch(void* const* d_in, const int* in_sizes, int n_in,
                              void* d_out, int out_size, void* d_ws, size_t ws_size,
                              hipStream_t stream) {
  const float* x     = (const float*)d_in[0];
  const float* n1w   = (const float*)d_in[1];
  const float* n1b   = (const float*)d_in[2];
  const float* qkvw  = (const float*)d_in[3];
  const float* qkvb  = (const float*)d_in[4];
  const float* btab  = (const float*)d_in[5];
  const float* projw = (const float*)d_in[6];
  const float* projb = (const float*)d_in[7];
  const float* n2w   = (const float*)d_in[8];
  const float* n2b   = (const float*)d_in[9];
  const float* w1    = (const float*)d_in[10];
  const float* b1    = (const float*)d_in[11];
  const float* w2    = (const float*)d_in[12];
  const float* b2    = (const float*)d_in[13];
  const float* mask  = (const float*)d_in[14];
  const int*   rel   = (const int*)d_in[15];
  float* out = (float*)d_out;
  bfr*   wsp = (bfr*)d_ws;   // (442368 + 98304) * 2 B ~= 1.08 MB

  k_prep<<<(WTOT+255)/256, 256, 0, stream>>>(qkvw, projw, w1, w2, wsp);
  k_prep2<<<(BMTOT+255)/256, 256, 0, stream>>>(btab, rel, mask, wsp + OBM);
  k_attn<<<NWIN, 256, 0, stream>>>(x, n1w, n1b, wsp, qkvb, projb, out);
  k_mlp<<<ROWS/64, 256, 0, stream>>>(out, n2w, n2b, wsp, b1, b2);
}

// Round 9
// 500.216 us; speedup vs baseline: 1.0671x; 1.0671x over previous
//
#include <hip/hip_runtime.h>
#include <math.h>

#define B_    32
#define HH    56
#define WW_   56
#define C_    192
#define WS_   7
#define SHIFT_ 3
#define HEADS_ 6
#define DH    32
#define N_    49
#define NWIN  2048
#define ROWS  100352
#define HID_  768
#define QKVN  576

typedef __bf16 bfr;
typedef __bf16 bf8 __attribute__((ext_vector_type(8)));
typedef __bf16 bf4 __attribute__((ext_vector_type(4)));
typedef float  f32x4 __attribute__((ext_vector_type(4)));

#define MFMA16(a,b,c) __builtin_amdgcn_mfma_f32_16x16x32_bf16(a,b,c,0,0,0)

// ---- ws layout (bf16 elements) ----
#define OQW   0         // qkvwT [576][192]
#define OPW   110592    // projwT[192][192]
#define OW1   147456    // w1T   [768][192]
#define OW2   294912    // w2T   [192][768]
#define OBM   442368    // bmask [6][4cls][64 q][64 k]  ROW-major q,k (pads=-1e30)
#define WTOT  442368
#define BMTOT 98304     // 6*4*64*64  (4 window classes: (wh==7)x(ww==7))

// ================= k_prep: transpose + fp32->bf16 all weights =================
__global__ __launch_bounds__(256) void k_prep(
    const float* __restrict__ qkvw, const float* __restrict__ projw,
    const float* __restrict__ w1,   const float* __restrict__ w2,
    bfr* __restrict__ wsp)
{
  int idx = blockIdx.x*256 + threadIdx.x;
  if (idx >= WTOT) return;
  if (idx < OPW)      { int i=idx;      int n=i/192, k=i%192; wsp[idx] = (bfr)qkvw[k*QKVN + n]; }
  else if (idx < OW1) { int i=idx-OPW;  int n=i/192, k=i%192; wsp[idx] = (bfr)projw[k*C_ + n]; }
  else if (idx < OW2) { int i=idx-OW1;  int n=i/192, k=i%192; wsp[idx] = (bfr)w1[k*HID_ + n]; }
  else                { int i=idx-OW2;  int n=i/768, k=i%768; wsp[idx] = (bfr)w2[k*C_ + n]; }
}

// ====== k_prep2: bmask[head][cls][q64][k64] = bias + mask (pads -1e30), k fastest ======
// Mask depends on (wh,ww) only through (wh==7, ww==7): 4 classes.
__global__ __launch_bounds__(256) void k_prep2(
    const float* __restrict__ btab, const int* __restrict__ rel,
    const float* __restrict__ mask, bfr* __restrict__ bm)
{
  int idx = blockIdx.x*256 + threadIdx.x;   // [head][cls][q][k] -- k fastest
  if (idx >= BMTOT) return;
  int k = idx & 63, q = (idx>>6) & 63, cls = (idx>>12) & 3, head = idx>>14;
  int wh = (cls & 2) ? 7 : 0, ww = (cls & 1) ? 7 : 0;
  int wi = wh*8 + ww;
  float v = -1e30f;
  if (q < N_ && k < N_) {
    int e = q*N_ + k;
    v = btab[rel[e]*HEADS_ + head] + mask[(size_t)wi*N_*N_ + e];
  }
  bm[idx] = (bfr)v;
}

// ================= Kernel 1: LN1+shift+QKV+attn+proj+residual, head-pair fused ============
// All LDS-bound MFMA outputs use SWAPPED operands (mfma(B,A,C) = D^T): lane then holds
// 4 consecutive COLUMNS (quad*4+r) of one token row (ln15) -> packed b64/b128 stores.
// LDS (bytes):
#define SM_HS 0        // bfr hs[64][200]          25600  (LN'd input, persists)
#define SM_QS 25600    // bfr qs[2][64][36]         9216
#define SM_KS 34816    // bfr ks[2][64][36]         9216
#define SM_VT 44032    // bfr vT[2][32][72]         9216
#define SM_P  53248    // bfr P[64][72]             9216  (wave-row-local scratch)
#define SM_OV 62464    // bfr ov2[64][72]           9216  (both heads: [row][hl*36+d])
#define SM_SR 71680    // int srows[64]              256
#define SM1_TOT 71936
#define HSP 200

__global__ __launch_bounds__(256, 2) void k_attn(
    const float* __restrict__ x,
    const float* __restrict__ n1w, const float* __restrict__ n1b,
    const bfr*   __restrict__ wsp,
    const float* __restrict__ qkvb,
    const float* __restrict__ projb,
    float* __restrict__ out)
{
  __shared__ char smem[SM1_TOT];
  bfr*   hs    = (bfr*)(smem + SM_HS);
  bfr*   qs    = (bfr*)(smem + SM_QS);
  bfr*   ks    = (bfr*)(smem + SM_KS);
  bfr*   vT    = (bfr*)(smem + SM_VT);
  bfr*   P     = (bfr*)(smem + SM_P);
  bfr*   ov2   = (bfr*)(smem + SM_OV);
  int*   srows = (int*)(smem + SM_SR);
  float* pj    = (float*)smem;   // overlay [64][196] fp32 = 50176 B over hs/qs/ks/vT

  const f32x4 ZERO4 = {0.f, 0.f, 0.f, 0.f};

  int win  = blockIdx.x;
  int tid  = threadIdx.x;
  int lane = tid & 63, wave = tid >> 6;
  int ln15 = lane & 15, quad = lane >> 4;
  int wi   = win & 63;
  int cls  = (((wi>>3)==7) ? 2 : 0) + (((wi&7)==7) ? 1 : 0);

  // ---- srows + zero hs pad rows (49..63 only) ----
  if (tid < N_) {
    int bb = win >> 6;
    int wh = wi >> 3, ww = wi & 7;
    int th = tid / WS_, tw = tid % WS_;
    int sh = wh*WS_ + th + SHIFT_; if (sh >= HH) sh -= HH;
    int sw = ww*WS_ + tw + SHIFT_; if (sw >= WW_) sw -= WW_;
    srows[tid] = bb*HH*WW_ + sh*WW_ + sw;
  }
  {
    int* hz = (int*)(hs + 49*HSP);
    for (int i = tid; i < 15*HSP/2; i += 256) hz[i] = 0;
  }
  __syncthreads();
  // ---- LN1 -> hs ----
  for (int r = wave; r < N_; r += 4) {
    const float* xr = x + (size_t)srows[r]*C_;
    float v0 = xr[lane], v1 = xr[lane+64], v2 = xr[lane+128];
    float s = v0+v1+v2, q = v0*v0+v1*v1+v2*v2;
    #pragma unroll
    for (int m = 32; m; m >>= 1) { s += __shfl_xor(s, m); q += __shfl_xor(q, m); }
    float mu = s*(1.f/C_), var = q*(1.f/C_) - mu*mu;
    float rs = rsqrtf(var + 1e-5f);
    hs[r*HSP + lane]     = (bfr)((v0-mu)*rs*n1w[lane]     + n1b[lane]);
    hs[r*HSP + lane+64]  = (bfr)((v1-mu)*rs*n1w[lane+64]  + n1b[lane+64]);
    hs[r*HSP + lane+128] = (bfr)((v2-mu)*rs*n1w[lane+128] + n1b[lane+128]);
  }
  __syncthreads();

  const bfr* qkvwT  = wsp + OQW;
  const bfr* projwT = wsp + OPW;
  const bfr* bmask  = wsp + OBM;

  f32x4 accp[3][4];   // proj accumulators (swapped layout: [outcol4][token]), persist
  #pragma unroll
  for (int j=0;j<3;j++)
    #pragma unroll
    for (int mt=0;mt<4;mt++) accp[j][mt] = ZERO4;

  for (int pair = 0; pair < 3; pair++) {
    // ---- QKV: q,k SWAPPED (packed col-stores); v normal (packed row-stores) ----
    {
      f32x4 qb0 = *(const f32x4*)&qkvb[       pair*64 + wave*16 + quad*4];
      f32x4 qb1 = *(const f32x4*)&qkvb[192  + pair*64 + wave*16 + quad*4];
      float qb2 =                 qkvb[384  + pair*64 + wave*16 + ln15];
      f32x4 acc[3][4];
      #pragma unroll
      for (int j=0;j<3;j++)
        #pragma unroll
        for (int mt=0;mt<4;mt++) acc[j][mt] = ZERO4;
      #pragma unroll
      for (int kk = 0; kk < 6; kk++) {
        bf8 afr[4];
        #pragma unroll
        for (int mt=0;mt<4;mt++)
          afr[mt] = *(const bf8*)&hs[(mt*16+ln15)*HSP + kk*32 + quad*8];
        bf8 bw0 = *(const bf8*)&qkvwT[(size_t)(      pair*64 + wave*16 + ln15)*192 + kk*32 + quad*8];
        bf8 bw1 = *(const bf8*)&qkvwT[(size_t)(192 + pair*64 + wave*16 + ln15)*192 + kk*32 + quad*8];
        bf8 bw2 = *(const bf8*)&qkvwT[(size_t)(384 + pair*64 + wave*16 + ln15)*192 + kk*32 + quad*8];
        #pragma unroll
        for (int mt=0;mt<4;mt++) {
          acc[0][mt] = MFMA16(bw0, afr[mt], acc[0][mt]);   // swapped -> D[qcol][token]
          acc[1][mt] = MFMA16(bw1, afr[mt], acc[1][mt]);   // swapped
          acc[2][mt] = MFMA16(afr[mt], bw2, acc[2][mt]);   // normal  -> D[token][vcol]
        }
      }
      int hlw = wave >> 1;
      int d0  = (wave & 1)*16 + quad*4;       // q/k col base (4 consecutive)
      int dv  = (wave & 1)*16 + ln15;         // v col (fixed per lane)
      #pragma unroll
      for (int mt=0;mt<4;mt++) {
        int token = mt*16 + ln15;
        bf4 pk;
        #pragma unroll
        for (int r=0;r<4;r++) pk[r] = (bfr)((acc[0][mt][r] + qb0[r])*0.17677669529663689f);
        *(bf4*)&qs[(hlw*64+token)*36 + d0] = pk;
        #pragma unroll
        for (int r=0;r<4;r++) pk[r] = (bfr)(acc[1][mt][r] + qb1[r]);
        *(bf4*)&ks[(hlw*64+token)*36 + d0] = pk;
        #pragma unroll
        for (int r=0;r<4;r++) pk[r] = (bfr)(acc[2][mt][r] + qb2);   // 4 consecutive tokens
        *(bf4*)&vT[(hlw*32+dv)*72 + mt*16 + quad*4] = pk;
      }
    }
    __syncthreads();

    // ---- bmask burst [q][k]: lane q=wave*16+ln15, 4 consecutive k ----
    bf4 bm4[2][4];
    #pragma unroll
    for (int hl = 0; hl < 2; hl++) {
      const bfr* bmh = bmask + (((size_t)(pair*2+hl)*4 + cls) << 12);
      #pragma unroll
      for (int nt = 0; nt < 4; nt++)
        bm4[hl][nt] = *(const bf4*)&bmh[(wave*16+ln15)*64 + nt*16 + quad*4];
    }

    // ---- QK^T SWAPPED: D[k][q]; lane holds 16 k-values for q=wave*16+ln15 ----
    float val[2][4][4];   // [hl][nt][r], k = nt*16+quad*4+r
    #pragma unroll
    for (int hl = 0; hl < 2; hl++) {
      bf8 aq = *(const bf8*)&qs[(hl*64 + wave*16 + ln15)*36 + quad*8];
      #pragma unroll
      for (int nt = 0; nt < 4; nt++) {
        f32x4 c;
        c[0] = (float)bm4[hl][nt][0]; c[1] = (float)bm4[hl][nt][1];
        c[2] = (float)bm4[hl][nt][2]; c[3] = (float)bm4[hl][nt][3];
        bf8 bk = *(const bf8*)&ks[(hl*64 + nt*16 + ln15)*36 + quad*8];
        c = MFMA16(bk, aq, c);                       // swapped
        #pragma unroll
        for (int r=0;r<4;r++) val[hl][nt][r] = c[r];
      }
    }

    // ---- proj-weight prefetch (6x 16B): latency hides under softmax ----
    bf8 pw[2][3];
    #pragma unroll
    for (int hl = 0; hl < 2; hl++)
      #pragma unroll
      for (int j = 0; j < 3; j++)
        pw[hl][j] = *(const bf8*)&projwT[(size_t)((wave*3+j)*16 + ln15)*192
                                         + (pair*2+hl)*32 + quad*8];

    // ---- per head: softmax (15 VALU + 2 shfl per reduce) + packed P + PV -> ov2 ----
    #pragma unroll
    for (int hl = 0; hl < 2; hl++) {
      float mx = val[hl][0][0];
      #pragma unroll
      for (int nt=0;nt<4;nt++)
        #pragma unroll
        for (int r=0;r<4;r++) mx = fmaxf(mx, val[hl][nt][r]);
      mx = fmaxf(mx, __shfl_xor(mx, 16));
      mx = fmaxf(mx, __shfl_xor(mx, 32));
      float sum = 0.f;
      #pragma unroll
      for (int nt=0;nt<4;nt++)
        #pragma unroll
        for (int r=0;r<4;r++) { val[hl][nt][r] = __expf(val[hl][nt][r] - mx); sum += val[hl][nt][r]; }
      sum += __shfl_xor(sum, 16);
      sum += __shfl_xor(sum, 32);
      float rsum = 1.f / sum;
      #pragma unroll
      for (int nt=0;nt<4;nt++) {
        bf4 pk;
        #pragma unroll
        for (int r=0;r<4;r++) pk[r] = (bfr)(val[hl][nt][r]*rsum);
        *(bf4*)&P[(wave*16+ln15)*72 + nt*16 + quad*4] = pk;     // own q-row, packed
      }
      // PV SWAPPED: D[d][q]; wave reads ONLY its own P rows -> no barrier
      bf8 ap0 = *(const bf8*)&P[(wave*16+ln15)*72 + quad*8];
      bf8 ap1 = *(const bf8*)&P[(wave*16+ln15)*72 + 32 + quad*8];
      #pragma unroll
      for (int nt = 0; nt < 2; nt++) {
        bf8 bv0 = *(const bf8*)&vT[(hl*32 + nt*16 + ln15)*72 + quad*8];
        bf8 bv1 = *(const bf8*)&vT[(hl*32 + nt*16 + ln15)*72 + 32 + quad*8];
        f32x4 c = MFMA16(bv0, ap0, ZERO4);
        c = MFMA16(bv1, ap1, c);
        bf4 pk;
        #pragma unroll
        for (int r=0;r<4;r++) pk[r] = (bfr)c[r];
        *(bf4*)&ov2[(wave*16+ln15)*72 + hl*36 + nt*16 + quad*4] = pk;
      }
    }
    __syncthreads();

    // ---- proj K-step SWAPPED (K=64: both heads), weights already in regs ----
    #pragma unroll
    for (int hl = 0; hl < 2; hl++) {
      bf8 afr[4];
      #pragma unroll
      for (int mt=0;mt<4;mt++)
        afr[mt] = *(const bf8*)&ov2[(mt*16+ln15)*72 + hl*36 + quad*8];
      #pragma unroll
      for (int j=0;j<3;j++)
        #pragma unroll
        for (int mt=0;mt<4;mt++) accp[j][mt] = MFMA16(pw[hl][j], afr[mt], accp[j][mt]);
    }
    // no barrier: next pair's QKV writes qs/ks/vT; all reads of them finished pre-ov2-barrier
  }

  // ---- epilogue: bias -> pj overlay (b128 packed) -> coalesced residual+scatter ----
  #pragma unroll
  for (int j=0;j<3;j++) {
    int col0 = (wave*3+j)*16 + quad*4;
    f32x4 pb = *(const f32x4*)&projb[col0];
    #pragma unroll
    for (int mt=0;mt<4;mt++) {
      f32x4 w;
      #pragma unroll
      for (int r=0;r<4;r++) w[r] = accp[j][mt][r] + pb[r];
      *(f32x4*)&pj[(mt*16+ln15)*196 + col0] = w;
    }
  }
  __syncthreads();
  for (int idx = tid; idx < N_*C_; idx += 256) {
    int n = idx / C_, c = idx % C_;
    size_t gr = (size_t)srows[n]*C_ + c;
    out[gr] = x[gr] + pj[n*196 + c];
  }
}

// ================= Kernel 2: LN2 + fc1 + GELU + fc2 + residual, 64 rows/block ================
// (R7 version: non-swapped, no spills — VGPR 88, FETCH ~50 MB, ~205 us measured.)
// LDS: ts[64][200] bf16 (25600) + hidc[64][200] bf16 (25600) = 51200 B.
// st f32[64][196] (50176) overlays ts+hidc after last use.
#define SM2_TS  0
#define SM2_HID 25600
#define SM2_TOT 51200

__global__ __launch_bounds__(256, 2) void k_mlp(
    float* __restrict__ y,
    const float* __restrict__ n2w, const float* __restrict__ n2b,
    const bfr* __restrict__ wsp,
    const float* __restrict__ b1, const float* __restrict__ b2)
{
  __shared__ char smem[SM2_TOT];
  bfr*   ts   = (bfr*)(smem + SM2_TS);
  bfr*   hidc = (bfr*)(smem + SM2_HID);
  float* st   = (float*)smem;       // overlay after ts/hidc dead

  const f32x4 ZERO4 = {0.f, 0.f, 0.f, 0.f};

  int r0 = blockIdx.x * 64;
  int tid = threadIdx.x;
  int lane = tid & 63, wave = tid >> 6;
  int ln15 = lane & 15, quad = lane >> 4;

  // ---- LN2 ----
  #pragma unroll
  for (int i = 0; i < 16; i++) {
    int r = wave + i*4;
    const float* yr = y + (size_t)(r0 + r)*C_;
    float v0 = yr[lane], v1 = yr[lane+64], v2 = yr[lane+128];
    float s = v0+v1+v2, q = v0*v0+v1*v1+v2*v2;
    #pragma unroll
    for (int m = 32; m; m >>= 1) { s += __shfl_xor(s, m); q += __shfl_xor(q, m); }
    float mu = s*(1.f/C_), var = q*(1.f/C_) - mu*mu;
    float rs = rsqrtf(var + 1e-5f);
    ts[r*HSP + lane]     = (bfr)((v0-mu)*rs*n2w[lane]     + n2b[lane]);
    ts[r*HSP + lane+64]  = (bfr)((v1-mu)*rs*n2w[lane+64]  + n2b[lane+64]);
    ts[r*HSP + lane+128] = (bfr)((v2-mu)*rs*n2w[lane+128] + n2b[lane+128]);
  }
  __syncthreads();

  const bfr* w1T = wsp + OW1;
  const bfr* w2T = wsp + OW2;

  f32x4 accp[3][4];   // fc2 accumulators, persist across chunks
  #pragma unroll
  for (int j=0;j<3;j++)
    #pragma unroll
    for (int mt=0;mt<4;mt++) accp[j][mt] = ZERO4;

  for (int c = 0; c < 4; c++) {
    // ---- fc1 weight burst (18x 16B) + b1 prefetch ----
    bf8 wf1[3][6];
    float bb[3];
    #pragma unroll
    for (int j=0;j<3;j++) {
      const bfr* wb = w1T + (size_t)((c*12 + wave*3 + j)*16 + ln15)*192 + quad*8;
      #pragma unroll
      for (int kk=0;kk<6;kk++)
        wf1[j][kk] = *(const bf8*)&wb[kk*32];
      bb[j] = b1[c*192 + (wave*3+j)*16 + ln15];
    }
    // ---- fc1 chunk: M=64, N=192, K=192, weights from regs ----
    f32x4 acc[3][4];
    #pragma unroll
    for (int j=0;j<3;j++)
      #pragma unroll
      for (int mt=0;mt<4;mt++) acc[j][mt] = ZERO4;
    #pragma unroll
    for (int kk = 0; kk < 6; kk++) {
      bf8 afr[4];
      #pragma unroll
      for (int mt=0;mt<4;mt++)
        afr[mt] = *(const bf8*)&ts[(mt*16+ln15)*HSP + kk*32 + quad*8];
      #pragma unroll
      for (int j=0;j<3;j++)
        #pragma unroll
        for (int mt=0;mt<4;mt++) acc[j][mt] = MFMA16(afr[mt], wf1[j][kk], acc[j][mt]);
    }
    // ---- fc2 weight burst issued per-j BEFORE that j's GELU (latency hides under VALU) ----
    bf8 wf2[3][6];
    #pragma unroll
    for (int j=0;j<3;j++) {
      const bfr* wb2 = w2T + (size_t)((wave*3+j)*16 + ln15)*768 + c*192 + quad*8;
      #pragma unroll
      for (int kk=0;kk<6;kk++)
        wf2[j][kk] = *(const bf8*)&wb2[kk*32];
      // GELU (tanh-form sigmoid; |err|<3e-4 << bf16 lsb)
      int colc = (wave*3 + j)*16 + ln15;
      #pragma unroll
      for (int mt=0;mt<4;mt++)
        #pragma unroll
        for (int r=0;r<4;r++) {
          int row = mt*16 + quad*4 + r;
          float g = acc[j][mt][r] + bb[j];
          float u = g*(1.5957691216f + 0.0713548170f*g*g);
          hidc[row*HSP + colc] = (bfr)(g / (1.f + __expf(-u)));
        }
    }
    __syncthreads();
    // ---- fc2 partial: M=64, N=192, K=192, weights from regs ----
    #pragma unroll
    for (int kk = 0; kk < 6; kk++) {
      bf8 afr[4];
      #pragma unroll
      for (int mt=0;mt<4;mt++)
        afr[mt] = *(const bf8*)&hidc[(mt*16+ln15)*HSP + kk*32 + quad*8];
      #pragma unroll
      for (int j=0;j<3;j++)
        #pragma unroll
        for (int mt=0;mt<4;mt++) accp[j][mt] = MFMA16(afr[mt], wf2[j][kk], accp[j][mt]);
    }
    __syncthreads();   // hidc reads done before next chunk's writes (or st overlay)
  }

  // ---- epilogue: bias -> st overlay (over ts/hidc, both dead) ----
  #pragma unroll
  for (int j=0;j<3;j++) {
    int col = (wave*3+j)*16 + ln15;
    float bb2 = b2[col];
    #pragma unroll
    for (int mt=0;mt<4;mt++)
      #pragma unroll
      for (int r=0;r<4;r++) {
        int row = mt*16 + quad*4 + r;
        st[row*196 + col] = accp[j][mt][r] + bb2;
      }
  }
  __syncthreads();
  // residual, coalesced, in-place
  for (int idx = tid; idx < 64*C_; idx += 256) {
    int r = idx / C_, c = idx % C_;
    size_t gr = (size_t)(r0 + r)*C_ + c;
    y[gr] = y[gr] + st[r*196 + c];
  }
}

extern "C" void kernel_launch(void* const* d_in, const int* in_sizes, int n_in,
                              void* d_out, int out_size, void* d_ws, size_t ws_size,
                              hipStream_t stream) {
  const float* x     = (const float*)d_in[0];
  const float* n1w   = (const float*)d_in[1];
  const float* n1b   = (const float*)d_in[2];
  const float* qkvw  = (const float*)d_in[3];
  const float* qkvb  = (const float*)d_in[4];
  const float* btab  = (const float*)d_in[5];
  const float* projw = (const float*)d_in[6];
  const float* projb = (const float*)d_in[7];
  const float* n2w   = (const float*)d_in[8];
  const float* n2b   = (const float*)d_in[9];
  const float* w1    = (const float*)d_in[10];
  const float* b1    = (const float*)d_in[11];
  const float* w2    = (const float*)d_in[12];
  const float* b2    = (const float*)d_in[13];
  const float* mask  = (const float*)d_in[14];
  const int*   rel   = (const int*)d_in[15];
  float* out = (float*)d_out;
  bfr*   wsp = (bfr*)d_ws;   // (442368 + 98304) * 2 B ~= 1.08 MB

  k_prep<<<(WTOT+255)/256, 256, 0, stream>>>(qkvw, projw, w1, w2, wsp);
  k_prep2<<<(BMTOT+255)/256, 256, 0, stream>>>(btab, rel, mask, wsp + OBM);
  k_attn<<<NWIN, 256, 0, stream>>>(x, n1w, n1b, wsp, qkvb, projb, out);
  k_mlp<<<ROWS/64, 256, 0, stream>>>(out, n2w, n2b, wsp, b1, b2);
}

// Round 10
// 466.275 us; speedup vs baseline: 1.1448x; 1.0728x over previous
//
#include <hip/hip_runtime.h>
#include <math.h>

#define B_    32
#define HH    56
#define WW_   56
#define C_    192
#define WS_   7
#define SHIFT_ 3
#define HEADS_ 6
#define DH    32
#define N_    49
#define NWIN  2048
#define ROWS  100352
#define HID_  768
#define QKVN  576

typedef __bf16 bfr;
typedef __bf16 bf8 __attribute__((ext_vector_type(8)));
typedef __bf16 bf4 __attribute__((ext_vector_type(4)));
typedef float  f32x4 __attribute__((ext_vector_type(4)));

#define MFMA16(a,b,c) __builtin_amdgcn_mfma_f32_16x16x32_bf16(a,b,c,0,0,0)

// ---- ws layout (bf16 elements) ----
#define OQW   0         // qkvwT [576][192]
#define OPW   110592    // projwT[192][192]
#define OW1   147456    // w1T   [768][192]
#define OW2   294912    // w2T   [192][768]
#define OBM   442368    // bmask [6][4cls][64 q][64 k]  ROW-major q,k (pads=-1e30)
#define WTOT  442368
#define BMTOT 98304     // 6*4*64*64  (4 window classes: (wh==7)x(ww==7))

// ================= k_prep: transpose + fp32->bf16 all weights =================
__global__ __launch_bounds__(256) void k_prep(
    const float* __restrict__ qkvw, const float* __restrict__ projw,
    const float* __restrict__ w1,   const float* __restrict__ w2,
    bfr* __restrict__ wsp)
{
  int idx = blockIdx.x*256 + threadIdx.x;
  if (idx >= WTOT) return;
  if (idx < OPW)      { int i=idx;      int n=i/192, k=i%192; wsp[idx] = (bfr)qkvw[k*QKVN + n]; }
  else if (idx < OW1) { int i=idx-OPW;  int n=i/192, k=i%192; wsp[idx] = (bfr)projw[k*C_ + n]; }
  else if (idx < OW2) { int i=idx-OW1;  int n=i/192, k=i%192; wsp[idx] = (bfr)w1[k*HID_ + n]; }
  else                { int i=idx-OW2;  int n=i/768, k=i%768; wsp[idx] = (bfr)w2[k*C_ + n]; }
}

// ====== k_prep2: bmask[head][cls][q64][k64] = bias + mask (pads -1e30), k fastest ======
// Mask depends on (wh,ww) only through (wh==7, ww==7): 4 classes.
__global__ __launch_bounds__(256) void k_prep2(
    const float* __restrict__ btab, const int* __restrict__ rel,
    const float* __restrict__ mask, bfr* __restrict__ bm)
{
  int idx = blockIdx.x*256 + threadIdx.x;   // [head][cls][q][k] -- k fastest
  if (idx >= BMTOT) return;
  int k = idx & 63, q = (idx>>6) & 63, cls = (idx>>12) & 3, head = idx>>14;
  int wh = (cls & 2) ? 7 : 0, ww = (cls & 1) ? 7 : 0;
  int wi = wh*8 + ww;
  float v = -1e30f;
  if (q < N_ && k < N_) {
    int e = q*N_ + k;
    v = btab[rel[e]*HEADS_ + head] + mask[(size_t)wi*N_*N_ + e];
  }
  bm[idx] = (bfr)v;
}

// ================= Kernel 1: LN1+shift+QKV+attn+proj+residual, head-pair fused ============
// Swapped-operand MFMA (mfma(B,A,C) = D^T) for packed b64/b128 LDS stores; row-local
// softmax (2 shuffles); x rows held in registers for the residual epilogue (LDS-capped
// at 2 blocks/CU -> VGPR free to 256).
// LDS (bytes):
#define SM_HS 0        // bfr hs[64][200]          25600  (LN'd input, persists)
#define SM_QS 25600    // bfr qs[2][64][36]         9216
#define SM_KS 34816    // bfr ks[2][64][36]         9216
#define SM_VT 44032    // bfr vT[2][32][72]         9216
#define SM_P  53248    // bfr P[64][72]             9216  (wave-row-local scratch)
#define SM_OV 62464    // bfr ov2[64][72]           9216  (both heads: [row][hl*36+d])
#define SM_SR 71680    // int srows[64]              256
#define SM1_TOT 71936
#define HSP 200

__global__ __launch_bounds__(256, 2) void k_attn(
    const float* __restrict__ x,
    const float* __restrict__ n1w, const float* __restrict__ n1b,
    const bfr*   __restrict__ wsp,
    const float* __restrict__ qkvb,
    const float* __restrict__ projb,
    float* __restrict__ out)
{
  __shared__ char smem[SM1_TOT];
  bfr*   hs    = (bfr*)(smem + SM_HS);
  bfr*   qs    = (bfr*)(smem + SM_QS);
  bfr*   ks    = (bfr*)(smem + SM_KS);
  bfr*   vT    = (bfr*)(smem + SM_VT);
  bfr*   P     = (bfr*)(smem + SM_P);
  bfr*   ov2   = (bfr*)(smem + SM_OV);
  int*   srows = (int*)(smem + SM_SR);
  float* pj    = (float*)smem;   // overlay [64][196] fp32 = 50176 B over hs/qs/ks/vT

  const f32x4 ZERO4 = {0.f, 0.f, 0.f, 0.f};

  int win  = blockIdx.x;
  int tid  = threadIdx.x;
  int lane = tid & 63, wave = tid >> 6;
  int ln15 = lane & 15, quad = lane >> 4;
  int wi   = win & 63;
  int cls  = (((wi>>3)==7) ? 2 : 0) + (((wi&7)==7) ? 1 : 0);

  // ---- srows + zero hs pad rows (49..63 only) ----
  if (tid < N_) {
    int bb = win >> 6;
    int wh = wi >> 3, ww = wi & 7;
    int th = tid / WS_, tw = tid % WS_;
    int sh = wh*WS_ + th + SHIFT_; if (sh >= HH) sh -= HH;
    int sw = ww*WS_ + tw + SHIFT_; if (sw >= WW_) sw -= WW_;
    srows[tid] = bb*HH*WW_ + sh*WW_ + sw;
  }
  {
    int* hz = (int*)(hs + 49*HSP);
    for (int i = tid; i < 15*HSP/2; i += 256) hz[i] = 0;
  }
  __syncthreads();
  // ---- LN1 -> hs, x rows kept in registers for the residual epilogue ----
  float xv0[13], xv1[13], xv2[13];
  #pragma unroll
  for (int i = 0; i < 13; i++) {
    int r = wave + i*4;
    if (r < N_) {
      const float* xr = x + (size_t)srows[r]*C_;
      float v0 = xr[lane], v1 = xr[lane+64], v2 = xr[lane+128];
      xv0[i] = v0; xv1[i] = v1; xv2[i] = v2;
      float s = v0+v1+v2, q = v0*v0+v1*v1+v2*v2;
      #pragma unroll
      for (int m = 32; m; m >>= 1) { s += __shfl_xor(s, m); q += __shfl_xor(q, m); }
      float mu = s*(1.f/C_), var = q*(1.f/C_) - mu*mu;
      float rs = rsqrtf(var + 1e-5f);
      hs[r*HSP + lane]     = (bfr)((v0-mu)*rs*n1w[lane]     + n1b[lane]);
      hs[r*HSP + lane+64]  = (bfr)((v1-mu)*rs*n1w[lane+64]  + n1b[lane+64]);
      hs[r*HSP + lane+128] = (bfr)((v2-mu)*rs*n1w[lane+128] + n1b[lane+128]);
    }
  }
  __syncthreads();

  const bfr* qkvwT  = wsp + OQW;
  const bfr* projwT = wsp + OPW;
  const bfr* bmask  = wsp + OBM;

  f32x4 accp[3][4];   // proj accumulators (swapped layout: [outcol4][token]), persist
  #pragma unroll
  for (int j=0;j<3;j++)
    #pragma unroll
    for (int mt=0;mt<4;mt++) accp[j][mt] = ZERO4;

  for (int pair = 0; pair < 3; pair++) {
    // ---- QKV: q,k SWAPPED (packed col-stores); v normal (packed row-stores) ----
    {
      f32x4 qb0 = *(const f32x4*)&qkvb[       pair*64 + wave*16 + quad*4];
      f32x4 qb1 = *(const f32x4*)&qkvb[192  + pair*64 + wave*16 + quad*4];
      float qb2 =                 qkvb[384  + pair*64 + wave*16 + ln15];
      f32x4 acc[3][4];
      #pragma unroll
      for (int j=0;j<3;j++)
        #pragma unroll
        for (int mt=0;mt<4;mt++) acc[j][mt] = ZERO4;
      #pragma unroll
      for (int kk = 0; kk < 6; kk++) {
        bf8 afr[4];
        #pragma unroll
        for (int mt=0;mt<4;mt++)
          afr[mt] = *(const bf8*)&hs[(mt*16+ln15)*HSP + kk*32 + quad*8];
        bf8 bw0 = *(const bf8*)&qkvwT[(size_t)(      pair*64 + wave*16 + ln15)*192 + kk*32 + quad*8];
        bf8 bw1 = *(const bf8*)&qkvwT[(size_t)(192 + pair*64 + wave*16 + ln15)*192 + kk*32 + quad*8];
        bf8 bw2 = *(const bf8*)&qkvwT[(size_t)(384 + pair*64 + wave*16 + ln15)*192 + kk*32 + quad*8];
        #pragma unroll
        for (int mt=0;mt<4;mt++) {
          acc[0][mt] = MFMA16(bw0, afr[mt], acc[0][mt]);   // swapped -> D[qcol][token]
          acc[1][mt] = MFMA16(bw1, afr[mt], acc[1][mt]);   // swapped
          acc[2][mt] = MFMA16(afr[mt], bw2, acc[2][mt]);   // normal  -> D[token][vcol]
        }
      }
      int hlw = wave >> 1;
      int d0  = (wave & 1)*16 + quad*4;       // q/k col base (4 consecutive)
      int dv  = (wave & 1)*16 + ln15;         // v col (fixed per lane)
      #pragma unroll
      for (int mt=0;mt<4;mt++) {
        int token = mt*16 + ln15;
        bf4 pk;
        #pragma unroll
        for (int r=0;r<4;r++) pk[r] = (bfr)((acc[0][mt][r] + qb0[r])*0.17677669529663689f);
        *(bf4*)&qs[(hlw*64+token)*36 + d0] = pk;
        #pragma unroll
        for (int r=0;r<4;r++) pk[r] = (bfr)(acc[1][mt][r] + qb1[r]);
        *(bf4*)&ks[(hlw*64+token)*36 + d0] = pk;
        #pragma unroll
        for (int r=0;r<4;r++) pk[r] = (bfr)(acc[2][mt][r] + qb2);   // 4 consecutive tokens
        *(bf4*)&vT[(hlw*32+dv)*72 + mt*16 + quad*4] = pk;
      }
    }
    __syncthreads();

    // ---- bmask burst [q][k]: lane q=wave*16+ln15, 4 consecutive k ----
    bf4 bm4[2][4];
    #pragma unroll
    for (int hl = 0; hl < 2; hl++) {
      const bfr* bmh = bmask + (((size_t)(pair*2+hl)*4 + cls) << 12);
      #pragma unroll
      for (int nt = 0; nt < 4; nt++)
        bm4[hl][nt] = *(const bf4*)&bmh[(wave*16+ln15)*64 + nt*16 + quad*4];
    }

    // ---- QK^T SWAPPED: D[k][q]; lane holds 16 k-values for q=wave*16+ln15 ----
    float val[2][4][4];   // [hl][nt][r], k = nt*16+quad*4+r
    #pragma unroll
    for (int hl = 0; hl < 2; hl++) {
      bf8 aq = *(const bf8*)&qs[(hl*64 + wave*16 + ln15)*36 + quad*8];
      #pragma unroll
      for (int nt = 0; nt < 4; nt++) {
        f32x4 c;
        c[0] = (float)bm4[hl][nt][0]; c[1] = (float)bm4[hl][nt][1];
        c[2] = (float)bm4[hl][nt][2]; c[3] = (float)bm4[hl][nt][3];
        bf8 bk = *(const bf8*)&ks[(hl*64 + nt*16 + ln15)*36 + quad*8];
        c = MFMA16(bk, aq, c);                       // swapped
        #pragma unroll
        for (int r=0;r<4;r++) val[hl][nt][r] = c[r];
      }
    }

    // ---- proj-weight prefetch (6x 16B): latency hides under softmax ----
    bf8 pw[2][3];
    #pragma unroll
    for (int hl = 0; hl < 2; hl++)
      #pragma unroll
      for (int j = 0; j < 3; j++)
        pw[hl][j] = *(const bf8*)&projwT[(size_t)((wave*3+j)*16 + ln15)*192
                                         + (pair*2+hl)*32 + quad*8];

    // ---- per head: softmax (15 VALU + 2 shfl per reduce) + packed P + PV -> ov2 ----
    #pragma unroll
    for (int hl = 0; hl < 2; hl++) {
      float mx = val[hl][0][0];
      #pragma unroll
      for (int nt=0;nt<4;nt++)
        #pragma unroll
        for (int r=0;r<4;r++) mx = fmaxf(mx, val[hl][nt][r]);
      mx = fmaxf(mx, __shfl_xor(mx, 16));
      mx = fmaxf(mx, __shfl_xor(mx, 32));
      float sum = 0.f;
      #pragma unroll
      for (int nt=0;nt<4;nt++)
        #pragma unroll
        for (int r=0;r<4;r++) { val[hl][nt][r] = __expf(val[hl][nt][r] - mx); sum += val[hl][nt][r]; }
      sum += __shfl_xor(sum, 16);
      sum += __shfl_xor(sum, 32);
      float rsum = 1.f / sum;
      #pragma unroll
      for (int nt=0;nt<4;nt++) {
        bf4 pk;
        #pragma unroll
        for (int r=0;r<4;r++) pk[r] = (bfr)(val[hl][nt][r]*rsum);
        *(bf4*)&P[(wave*16+ln15)*72 + nt*16 + quad*4] = pk;     // own q-row, packed
      }
      // PV SWAPPED: D[d][q]; wave reads ONLY its own P rows -> no barrier
      bf8 ap0 = *(const bf8*)&P[(wave*16+ln15)*72 + quad*8];
      bf8 ap1 = *(const bf8*)&P[(wave*16+ln15)*72 + 32 + quad*8];
      #pragma unroll
      for (int nt = 0; nt < 2; nt++) {
        bf8 bv0 = *(const bf8*)&vT[(hl*32 + nt*16 + ln15)*72 + quad*8];
        bf8 bv1 = *(const bf8*)&vT[(hl*32 + nt*16 + ln15)*72 + 32 + quad*8];
        f32x4 c = MFMA16(bv0, ap0, ZERO4);
        c = MFMA16(bv1, ap1, c);
        bf4 pk;
        #pragma unroll
        for (int r=0;r<4;r++) pk[r] = (bfr)c[r];
        *(bf4*)&ov2[(wave*16+ln15)*72 + hl*36 + nt*16 + quad*4] = pk;
      }
    }
    __syncthreads();

    // ---- proj K-step SWAPPED (K=64: both heads), weights already in regs ----
    #pragma unroll
    for (int hl = 0; hl < 2; hl++) {
      bf8 afr[4];
      #pragma unroll
      for (int mt=0;mt<4;mt++)
        afr[mt] = *(const bf8*)&ov2[(mt*16+ln15)*72 + hl*36 + quad*8];
      #pragma unroll
      for (int j=0;j<3;j++)
        #pragma unroll
        for (int mt=0;mt<4;mt++) accp[j][mt] = MFMA16(pw[hl][j], afr[mt], accp[j][mt]);
    }
    // no barrier: next pair's QKV writes qs/ks/vT; all reads of them finished pre-ov2-barrier
  }

  // ---- epilogue: bias -> pj overlay (b128 packed) -> residual from regs + scatter ----
  #pragma unroll
  for (int j=0;j<3;j++) {
    int col0 = (wave*3+j)*16 + quad*4;
    f32x4 pb = *(const f32x4*)&projb[col0];
    #pragma unroll
    for (int mt=0;mt<4;mt++) {
      f32x4 w;
      #pragma unroll
      for (int r=0;r<4;r++) w[r] = accp[j][mt][r] + pb[r];
      *(f32x4*)&pj[(mt*16+ln15)*196 + col0] = w;
    }
  }
  __syncthreads();
  #pragma unroll
  for (int i = 0; i < 13; i++) {
    int r = wave + i*4;
    if (r < N_) {
      float* orow = out + (size_t)srows[r]*C_;
      orow[lane]     = xv0[i] + pj[r*196 + lane];
      orow[lane+64]  = xv1[i] + pj[r*196 + lane+64];
      orow[lane+128] = xv2[i] + pj[r*196 + lane+128];
    }
  }
}

// ================= Kernel 2: LN2 + fc1 + GELU + fc2 + residual, 64 rows/block ================
// SWAPPED operands with IN-LOOP weight loads (no burst arrays -> no R8 spills):
// packed b64 hidc stores, b128 st stores. launch_bounds(256,3) caps VGPR ~170 so the
// LDS-allowed 3 blocks/CU (3 waves/SIMD) stay resident.
// LDS: ts[64][200] (25600) + hidc[64][200] (25600) = 51200 B.
#define SM2_TS  0
#define SM2_HID 25600
#define SM2_TOT 51200

__global__ __launch_bounds__(256, 3) void k_mlp(
    float* __restrict__ y,
    const float* __restrict__ n2w, const float* __restrict__ n2b,
    const bfr* __restrict__ wsp,
    const float* __restrict__ b1, const float* __restrict__ b2)
{
  __shared__ char smem[SM2_TOT];
  bfr*   ts   = (bfr*)(smem + SM2_TS);
  bfr*   hidc = (bfr*)(smem + SM2_HID);
  float* st   = (float*)smem;       // overlay after ts/hidc dead

  const f32x4 ZERO4 = {0.f, 0.f, 0.f, 0.f};

  int r0 = blockIdx.x * 64;
  int tid = threadIdx.x;
  int lane = tid & 63, wave = tid >> 6;
  int ln15 = lane & 15, quad = lane >> 4;

  // ---- LN2 ----
  #pragma unroll
  for (int i = 0; i < 16; i++) {
    int r = wave + i*4;
    const float* yr = y + (size_t)(r0 + r)*C_;
    float v0 = yr[lane], v1 = yr[lane+64], v2 = yr[lane+128];
    float s = v0+v1+v2, q = v0*v0+v1*v1+v2*v2;
    #pragma unroll
    for (int m = 32; m; m >>= 1) { s += __shfl_xor(s, m); q += __shfl_xor(q, m); }
    float mu = s*(1.f/C_), var = q*(1.f/C_) - mu*mu;
    float rs = rsqrtf(var + 1e-5f);
    ts[r*HSP + lane]     = (bfr)((v0-mu)*rs*n2w[lane]     + n2b[lane]);
    ts[r*HSP + lane+64]  = (bfr)((v1-mu)*rs*n2w[lane+64]  + n2b[lane+64]);
    ts[r*HSP + lane+128] = (bfr)((v2-mu)*rs*n2w[lane+128] + n2b[lane+128]);
  }
  __syncthreads();

  const bfr* w1T = wsp + OW1;
  const bfr* w2T = wsp + OW2;

  f32x4 accp[3][4];   // fc2 accumulators (swapped layout: [outcol4][token]), persist
  #pragma unroll
  for (int j=0;j<3;j++)
    #pragma unroll
    for (int mt=0;mt<4;mt++) accp[j][mt] = ZERO4;

  for (int c = 0; c < 4; c++) {
    // ---- fc1 chunk SWAPPED: D[hidcol][token]; weights loaded in-loop ----
    f32x4 acc[3][4];
    #pragma unroll
    for (int j=0;j<3;j++)
      #pragma unroll
      for (int mt=0;mt<4;mt++) acc[j][mt] = ZERO4;
    #pragma unroll
    for (int kk = 0; kk < 6; kk++) {
      bf8 afr[4];
      #pragma unroll
      for (int mt=0;mt<4;mt++)
        afr[mt] = *(const bf8*)&ts[(mt*16+ln15)*HSP + kk*32 + quad*8];
      #pragma unroll
      for (int j=0;j<3;j++) {
        bf8 bw = *(const bf8*)&w1T[(size_t)((c*12 + wave*3 + j)*16 + ln15)*192
                                   + kk*32 + quad*8];
        #pragma unroll
        for (int mt=0;mt<4;mt++) acc[j][mt] = MFMA16(bw, afr[mt], acc[j][mt]);
      }
    }
    // ---- GELU (tanh-form sigmoid; |err|<3e-4 << bf16 lsb) + packed b64 stores ----
    #pragma unroll
    for (int j=0;j<3;j++) {
      f32x4 bbv = *(const f32x4*)&b1[c*192 + (wave*3+j)*16 + quad*4];
      int colc0 = (wave*3 + j)*16 + quad*4;
      #pragma unroll
      for (int mt=0;mt<4;mt++) {
        bf4 pk;
        #pragma unroll
        for (int r=0;r<4;r++) {
          float g = acc[j][mt][r] + bbv[r];
          float u = g*(1.5957691216f + 0.0713548170f*g*g);
          pk[r] = (bfr)(g / (1.f + __expf(-u)));
        }
        *(bf4*)&hidc[(mt*16+ln15)*HSP + colc0] = pk;
      }
    }
    __syncthreads();
    // ---- fc2 partial SWAPPED: accp = D[outcol][token]; weights in-loop ----
    #pragma unroll
    for (int kk = 0; kk < 6; kk++) {
      bf8 afr[4];
      #pragma unroll
      for (int mt=0;mt<4;mt++)
        afr[mt] = *(const bf8*)&hidc[(mt*16+ln15)*HSP + kk*32 + quad*8];
      #pragma unroll
      for (int j=0;j<3;j++) {
        bf8 bw = *(const bf8*)&w2T[(size_t)((wave*3+j)*16 + ln15)*768
                                   + c*192 + kk*32 + quad*8];
        #pragma unroll
        for (int mt=0;mt<4;mt++) accp[j][mt] = MFMA16(bw, afr[mt], accp[j][mt]);
      }
    }
    __syncthreads();   // hidc reads done before next chunk's writes (or st overlay)
  }

  // ---- epilogue: bias -> st overlay (b128 packed; over ts/hidc, both dead) ----
  #pragma unroll
  for (int j=0;j<3;j++) {
    int col0 = (wave*3+j)*16 + quad*4;
    f32x4 bb2 = *(const f32x4*)&b2[col0];
    #pragma unroll
    for (int mt=0;mt<4;mt++) {
      f32x4 w;
      #pragma unroll
      for (int r=0;r<4;r++) w[r] = accp[j][mt][r] + bb2[r];
      *(f32x4*)&st[(mt*16+ln15)*196 + col0] = w;
    }
  }
  __syncthreads();
  // residual, coalesced, in-place
  for (int idx = tid; idx < 64*C_; idx += 256) {
    int r = idx / C_, c = idx % C_;
    size_t gr = (size_t)(r0 + r)*C_ + c;
    y[gr] = y[gr] + st[r*196 + c];
  }
}

extern "C" void kernel_launch(void* const* d_in, const int* in_sizes, int n_in,
                              void* d_out, int out_size, void* d_ws, size_t ws_size,
                              hipStream_t stream) {
  const float* x     = (const float*)d_in[0];
  const float* n1w   = (const float*)d_in[1];
  const float* n1b   = (const float*)d_in[2];
  const float* qkvw  = (const float*)d_in[3];
  const float* qkvb  = (const float*)d_in[4];
  const float* btab  = (const float*)d_in[5];
  const float* projw = (const float*)d_in[6];
  const float* projb = (const float*)d_in[7];
  const float* n2w   = (const float*)d_in[8];
  const float* n2b   = (const float*)d_in[9];
  const float* w1    = (const float*)d_in[10];
  const float* b1    = (const float*)d_in[11];
  const float* w2    = (const float*)d_in[12];
  const float* b2    = (const float*)d_in[13];
  const float* mask  = (const float*)d_in[14];
  const int*   rel   = (const int*)d_in[15];
  float* out = (float*)d_out;
  bfr*   wsp = (bfr*)d_ws;   // (442368 + 98304) * 2 B ~= 1.08 MB

  k_prep<<<(WTOT+255)/256, 256, 0, stream>>>(qkvw, projw, w1, w2, wsp);
  k_prep2<<<(BMTOT+255)/256, 256, 0, stream>>>(btab, rel, mask, wsp + OBM);
  k_attn<<<NWIN, 256, 0, stream>>>(x, n1w, n1b, wsp, qkvb, projb, out);
  k_mlp<<<ROWS/64, 256, 0, stream>>>(out, n2w, n2b, wsp, b1, b2);
}